// Round 7
// baseline (1506.088 us; speedup 1.0000x reference)
//
#include <hip/hip_runtime.h>
#include <stdint.h>

#define SEQ 4096
#define DIM 1024

typedef unsigned short u16;

__device__ __forceinline__ u16 f2bf(float f) {
    unsigned u = __float_as_uint(f);
    u += 0x7fffu + ((u >> 16) & 1u);
    return (u16)(u >> 16);
}
__device__ __forceinline__ float bf2f(u16 h) {
    return __uint_as_float(((unsigned)h) << 16);
}

__device__ __forceinline__ void stc(u16* p, float v)   { *p = f2bf(v); }
__device__ __forceinline__ void stc(float* p, float v) { *p = v; }

// ---------------------------------------------------------------------------
// Kernel 1: h[s,:] = rmsnorm(emb[x[s],:]) * norm_w   (all fp32, eps=FLT_EPS)
// x int32 (established R3==R4); int64 guard kept as free insurance.
// ---------------------------------------------------------------------------
__global__ __launch_bounds__(256) void embed_rmsnorm(
    const int* __restrict__ x, const float* __restrict__ emb,
    const float* __restrict__ nw, float* __restrict__ h)
{
    const int row  = blockIdx.x;
    const int t    = threadIdx.x;
    const int lane = t & 63, wave = t >> 6;

    bool i64 = true;
    #pragma unroll
    for (int i = 1; i < 128; i += 2) i64 = i64 && (x[i] == 0);
    const int id = i64 ? x[2 * row] : x[row];

    float4 e = *(const float4*)(emb + (size_t)id * DIM + t * 4);
    float ss = e.x*e.x + e.y*e.y + e.z*e.z + e.w*e.w;
    #pragma unroll
    for (int off = 32; off > 0; off >>= 1) ss += __shfl_down(ss, off);

    __shared__ float red[4];
    if (lane == 0) red[wave] = ss;
    __syncthreads();
    float sum = red[0] + red[1] + red[2] + red[3];
    float scale = rsqrtf(sum * (1.0f / DIM) + 1.1920929e-7f);  // fp32 eps

    float4 n = *(const float4*)(nw + t * 4);
    float4 o;
    o.x = e.x * scale * n.x;
    o.y = e.y * scale * n.y;
    o.z = e.z * scale * n.z;
    o.w = e.w * scale * n.w;
    *(float4*)(h + (size_t)row * DIM + t * 4) = o;
}

// ---------------------------------------------------------------------------
// Kernel 2: C[M,N] = A[M,K](fp32) * B[N,K]^T(fp32) — fp32 VALU.
// 64x64 tile, BK=16, 256 threads, 4x4 outputs/thread. CT: float or u16.
// ---------------------------------------------------------------------------
template<typename CT>
__global__ __launch_bounds__(256) void gemm_abt(
    const float* __restrict__ A, int lda,
    const float* __restrict__ B, int ldb,
    CT* __restrict__ C, int ldc, int K)
{
    __shared__ float Asz[16][64];   // Asz[k][m]
    __shared__ float Bsz[16][64];   // Bsz[k][n]

    const int tid = threadIdx.x;
    const int tx = tid & 15, ty = tid >> 4;
    const int m0 = blockIdx.y * 64, n0 = blockIdx.x * 64;
    const int lr = tid >> 2;          // loader row 0..63
    const int lk = (tid & 3) * 4;     // loader k-quad

    float acc[4][4] = {};

    for (int k0 = 0; k0 < K; k0 += 16) {
        float4 av = *(const float4*)(A + (size_t)(m0 + lr) * lda + k0 + lk);
        float4 bv = *(const float4*)(B + (size_t)(n0 + lr) * ldb + k0 + lk);
        __syncthreads();
        Asz[lk+0][lr] = av.x; Asz[lk+1][lr] = av.y; Asz[lk+2][lr] = av.z; Asz[lk+3][lr] = av.w;
        Bsz[lk+0][lr] = bv.x; Bsz[lk+1][lr] = bv.y; Bsz[lk+2][lr] = bv.z; Bsz[lk+3][lr] = bv.w;
        __syncthreads();
        #pragma unroll
        for (int kk = 0; kk < 16; ++kk) {
            float4 a4 = *(const float4*)&Asz[kk][ty * 4];
            float4 b4 = *(const float4*)&Bsz[kk][tx * 4];
            float a[4] = {a4.x, a4.y, a4.z, a4.w};
            float b[4] = {b4.x, b4.y, b4.z, b4.w};
            #pragma unroll
            for (int i = 0; i < 4; ++i)
                #pragma unroll
                for (int j = 0; j < 4; ++j)
                    acc[i][j] = fmaf(a[i], b[j], acc[i][j]);
        }
    }

    #pragma unroll
    for (int i = 0; i < 4; ++i)
        #pragma unroll
        for (int j = 0; j < 4; ++j)
            stc(C + (size_t)(m0 + ty*4 + i) * ldc + (n0 + tx*4 + j), acc[i][j]);
}

// ---------------------------------------------------------------------------
// Kernel 3: out[M,N] = silu(P[M,K](fp32) @ v[K,N](bf16)) — FP32 output.
// ---------------------------------------------------------------------------
__global__ __launch_bounds__(256) void gemm_ab_silu(
    const float* __restrict__ A, int lda,
    const u16* __restrict__ B, int ldb,
    float* __restrict__ C, int ldc, int K)
{
    __shared__ float Asz[16][64];   // Asz[k][m]
    __shared__ float Bs[16][64];    // Bs[k][n]

    const int tid = threadIdx.x;
    const int tx = tid & 15, ty = tid >> 4;
    const int m0 = blockIdx.y * 64, n0 = blockIdx.x * 64;
    const int lr = tid >> 2,  lk = (tid & 3) * 4;    // A loader
    const int br = tid >> 4,  bc = (tid & 15) * 4;   // B loader

    float acc[4][4] = {};

    for (int k0 = 0; k0 < K; k0 += 16) {
        float4  av = *(const float4*)(A + (size_t)(m0 + lr) * lda + k0 + lk);
        ushort4 bv = *(const ushort4*)(B + (size_t)(k0 + br) * ldb + n0 + bc);
        __syncthreads();
        Asz[lk+0][lr] = av.x; Asz[lk+1][lr] = av.y; Asz[lk+2][lr] = av.z; Asz[lk+3][lr] = av.w;
        Bs[br][bc+0] = bf2f(bv.x); Bs[br][bc+1] = bf2f(bv.y);
        Bs[br][bc+2] = bf2f(bv.z); Bs[br][bc+3] = bf2f(bv.w);
        __syncthreads();
        #pragma unroll
        for (int kk = 0; kk < 16; ++kk) {
            float4 a4 = *(const float4*)&Asz[kk][ty * 4];
            float4 b4 = *(const float4*)&Bs[kk][tx * 4];
            float a[4] = {a4.x, a4.y, a4.z, a4.w};
            float b[4] = {b4.x, b4.y, b4.z, b4.w};
            #pragma unroll
            for (int i = 0; i < 4; ++i)
                #pragma unroll
                for (int j = 0; j < 4; ++j)
                    acc[i][j] = fmaf(a[i], b[j], acc[i][j]);
        }
    }

    #pragma unroll
    for (int i = 0; i < 4; ++i)
        #pragma unroll
        for (int j = 0; j < 4; ++j) {
            float v = acc[i][j];
            v = v / (1.0f + __expf(-v));   // silu
            C[(size_t)(m0 + ty*4 + i) * ldc + (n0 + tx*4 + j)] = v;
        }
}

// ---------------------------------------------------------------------------
// Kernel 4: row softmax over fp32 [SEQ, SEQ], fp32 in-place.
// ---------------------------------------------------------------------------
__global__ __launch_bounds__(256) void softmax_rows(float* __restrict__ S)
{
    const int row  = blockIdx.x;
    const int t    = threadIdx.x;
    const int lane = t & 63, wave = t >> 6;
    float* rp = S + (size_t)row * SEQ;

    float v[16];
    #pragma unroll
    for (int i = 0; i < 4; ++i) {
        float4 f = *(const float4*)(rp + i * 1024 + t * 4);
        v[i*4+0] = f.x; v[i*4+1] = f.y; v[i*4+2] = f.z; v[i*4+3] = f.w;
    }

    float m = v[0];
    #pragma unroll
    for (int i = 1; i < 16; ++i) m = fmaxf(m, v[i]);
    #pragma unroll
    for (int off = 32; off > 0; off >>= 1) m = fmaxf(m, __shfl_down(m, off));
    __shared__ float red[4];
    if (lane == 0) red[wave] = m;
    __syncthreads();
    m = fmaxf(fmaxf(red[0], red[1]), fmaxf(red[2], red[3]));
    __syncthreads();

    float s = 0.0f;
    #pragma unroll
    for (int i = 0; i < 16; ++i) { v[i] = __expf(v[i] - m); s += v[i]; }
    #pragma unroll
    for (int off = 32; off > 0; off >>= 1) s += __shfl_down(s, off);
    if (lane == 0) red[wave] = s;
    __syncthreads();
    s = red[0] + red[1] + red[2] + red[3];
    float inv = 1.0f / s;

    #pragma unroll
    for (int i = 0; i < 4; ++i) {
        float4 o;
        o.x = v[i*4+0] * inv; o.y = v[i*4+1] * inv;
        o.z = v[i*4+2] * inv; o.w = v[i*4+3] * inv;
        *(float4*)(rp + i * 1024 + t * 4) = o;
    }
}

// ---------------------------------------------------------------------------
extern "C" void kernel_launch(void* const* d_in, const int* in_sizes, int n_in,
                              void* d_out, int out_size, void* d_ws, size_t ws_size,
                              hipStream_t stream)
{
    // x int32; emb/norm_w/Wq/Wk/Wv fp32; OUTPUT fp32 (reference returns fp32)
    const int*   x   = (const int*)d_in[0];
    const float* emb = (const float*)d_in[1];
    const float* nw  = (const float*)d_in[2];
    const float* Wq  = (const float*)d_in[3];
    const float* Wk  = (const float*)d_in[4];
    const float* Wv  = (const float*)d_in[5];
    float* out = (float*)d_out;

    // ws layout (104 MB; h overlaps Sc head — h dies before Sc GEMM writes):
    char* ws = (char*)d_ws;
    float* q  = (float*)(ws);                   // [ 0,16) MB [SEQ,DIM] fp32
    float* k  = (float*)(ws + (16u << 20));     // [16,32) MB [SEQ,DIM] fp32
    u16*   v  = (u16*)  (ws + (32u << 20));     // [32,40) MB [SEQ,DIM] bf16
    float* Sc = (float*)(ws + (40u << 20));     // [40,104) MB [SEQ,SEQ] fp32
    float* h  = (float*)(ws + (40u << 20));     // [40,56) MB [SEQ,DIM] fp32

    embed_rmsnorm<<<SEQ, 256, 0, stream>>>(x, emb, nw, h);

    dim3 gqkv(DIM / 64, SEQ / 64);
    gemm_abt<float><<<gqkv, 256, 0, stream>>>(h, DIM, Wq, DIM, q, DIM, DIM);
    gemm_abt<float><<<gqkv, 256, 0, stream>>>(h, DIM, Wk, DIM, k, DIM, DIM);
    gemm_abt<u16>  <<<gqkv, 256, 0, stream>>>(h, DIM, Wv, DIM, v, DIM, DIM);

    dim3 gs(SEQ / 64, SEQ / 64);
    gemm_abt<float><<<gs, 256, 0, stream>>>(q, DIM, k, DIM, Sc, SEQ, DIM);

    softmax_rows<<<SEQ, 256, 0, stream>>>(Sc);

    dim3 gpv(DIM / 64, SEQ / 64);
    gemm_ab_silu<<<gpv, 256, 0, stream>>>(Sc, SEQ, v, DIM, out, DIM, SEQ);
}

// Round 8
// 632.135 us; speedup vs baseline: 2.3825x; 2.3825x over previous
//
#include <hip/hip_runtime.h>
#include <stdint.h>

#define SEQ 4096
#define DIM 1024

typedef __bf16 bf16x8 __attribute__((ext_vector_type(8)));
typedef float f32x4 __attribute__((ext_vector_type(4)));
typedef unsigned short u16;

__device__ __forceinline__ u16 f2bf(float f) {
    unsigned u = __float_as_uint(f);
    u += 0x7fffu + ((u >> 16) & 1u);     // RNE
    return (u16)(u >> 16);
}
__device__ __forceinline__ float bf2f(u16 h) {
    return __uint_as_float(((unsigned)h) << 16);
}

__device__ __forceinline__ void stc(u16* p, float v)   { *p = f2bf(v); }
__device__ __forceinline__ void stc(float* p, float v) { *p = v; }

// ---------------------------------------------------------------------------
// Kernel 1: h[s,:] = rmsnorm(emb[x[s],:]) * norm_w   (all fp32, eps=FLT_EPS)
// ---------------------------------------------------------------------------
__global__ __launch_bounds__(256) void embed_rmsnorm(
    const int* __restrict__ x, const float* __restrict__ emb,
    const float* __restrict__ nw, float* __restrict__ h)
{
    const int row  = blockIdx.x;
    const int t    = threadIdx.x;
    const int lane = t & 63, wave = t >> 6;

    bool i64 = true;
    #pragma unroll
    for (int i = 1; i < 128; i += 2) i64 = i64 && (x[i] == 0);
    const int id = i64 ? x[2 * row] : x[row];

    float4 e = *(const float4*)(emb + (size_t)id * DIM + t * 4);
    float ss = e.x*e.x + e.y*e.y + e.z*e.z + e.w*e.w;
    #pragma unroll
    for (int off = 32; off > 0; off >>= 1) ss += __shfl_down(ss, off);

    __shared__ float red[4];
    if (lane == 0) red[wave] = ss;
    __syncthreads();
    float sum = red[0] + red[1] + red[2] + red[3];
    float scale = rsqrtf(sum * (1.0f / DIM) + 1.1920929e-7f);  // fp32 eps

    float4 n = *(const float4*)(nw + t * 4);
    float4 o;
    o.x = e.x * scale * n.x;
    o.y = e.y * scale * n.y;
    o.z = e.z * scale * n.z;
    o.w = e.w * scale * n.w;
    *(float4*)(h + (size_t)row * DIM + t * 4) = o;
}

// ---------------------------------------------------------------------------
// Kernel 2: split-precision MFMA GEMM, fp32 inputs: C[M,N] = A[M,K]*B[N,K]^T
// Stages hi/lo bf16 pairs in LDS; acc = AhBh + AhBl + AlBh (~fp32 accuracy,
// residual ~2^-16 rel). 128x128 tile, BK=32, 4 waves, 4x4 MFMAs/wave.
// Retro-validated by R3==R4 bit-identical output. CT float or u16(bf16).
// TRANSC stores C^T.
// ---------------------------------------------------------------------------
template<typename CT, bool TRANSC>
__global__ __launch_bounds__(256, 2) void gemm_f32in(
    const float* __restrict__ A, int lda,
    const float* __restrict__ B, int ldb,
    CT* __restrict__ C, int ldc, int K)
{
    __shared__ __align__(16) u16 Ash[128 * 32];
    __shared__ __align__(16) u16 Asl[128 * 32];
    __shared__ __align__(16) u16 Bsh[128 * 32];
    __shared__ __align__(16) u16 Bsl[128 * 32];

    const int tid  = threadIdx.x;
    const int lane = tid & 63;
    const int wave = tid >> 6;
    const int m0   = blockIdx.y * 128;
    const int n0   = blockIdx.x * 128;
    const int wr   = (wave >> 1) * 64;
    const int wc   = (wave & 1) * 64;
    const int half = lane >> 4;
    const int l16  = lane & 15;

    f32x4 acc[4][4] = {};

    const int arow = tid >> 2;          // row within 64-row half
    const int acol = (tid & 3) * 8;     // 8 consecutive k per thread

    for (int k0 = 0; k0 < K; k0 += 32) {
        const float* pa0 = A + (size_t)(m0 + arow)      * lda + k0 + acol;
        const float* pa1 = A + (size_t)(m0 + 64 + arow) * lda + k0 + acol;
        const float* pb0 = B + (size_t)(n0 + arow)      * ldb + k0 + acol;
        const float* pb1 = B + (size_t)(n0 + 64 + arow) * ldb + k0 + acol;
        float v[4][8];
        #pragma unroll
        for (int m = 0; m < 4; ++m) {
            const float* p = (m == 0) ? pa0 : (m == 1) ? pa1 : (m == 2) ? pb0 : pb1;
            float4 f0 = *(const float4*)(p);
            float4 f1 = *(const float4*)(p + 4);
            v[m][0]=f0.x; v[m][1]=f0.y; v[m][2]=f0.z; v[m][3]=f0.w;
            v[m][4]=f1.x; v[m][5]=f1.y; v[m][6]=f1.z; v[m][7]=f1.w;
        }

        __syncthreads();   // prior iteration's LDS reads complete
        u16* dsth[4] = { &Ash[tid*8], &Ash[2048+tid*8], &Bsh[tid*8], &Bsh[2048+tid*8] };
        u16* dstl[4] = { &Asl[tid*8], &Asl[2048+tid*8], &Bsl[tid*8], &Bsl[2048+tid*8] };
        #pragma unroll
        for (int m = 0; m < 4; ++m) {
            ushort4 h0, h1, l0, l1;
            u16 hh;
            hh = f2bf(v[m][0]); h0.x = hh; l0.x = f2bf(v[m][0] - bf2f(hh));
            hh = f2bf(v[m][1]); h0.y = hh; l0.y = f2bf(v[m][1] - bf2f(hh));
            hh = f2bf(v[m][2]); h0.z = hh; l0.z = f2bf(v[m][2] - bf2f(hh));
            hh = f2bf(v[m][3]); h0.w = hh; l0.w = f2bf(v[m][3] - bf2f(hh));
            hh = f2bf(v[m][4]); h1.x = hh; l1.x = f2bf(v[m][4] - bf2f(hh));
            hh = f2bf(v[m][5]); h1.y = hh; l1.y = f2bf(v[m][5] - bf2f(hh));
            hh = f2bf(v[m][6]); h1.z = hh; l1.z = f2bf(v[m][6] - bf2f(hh));
            hh = f2bf(v[m][7]); h1.w = hh; l1.w = f2bf(v[m][7] - bf2f(hh));
            *(ushort4*)(dsth[m])     = h0;
            *(ushort4*)(dsth[m] + 4) = h1;
            *(ushort4*)(dstl[m])     = l0;
            *(ushort4*)(dstl[m] + 4) = l1;
        }
        __syncthreads();

        bf16x8 afh[4], afl[4], bfh[4], bfl[4];
        #pragma unroll
        for (int i = 0; i < 4; ++i) {
            afh[i] = *(const bf16x8*)&Ash[(wr + i*16 + l16) * 32 + half * 8];
            afl[i] = *(const bf16x8*)&Asl[(wr + i*16 + l16) * 32 + half * 8];
        }
        #pragma unroll
        for (int j = 0; j < 4; ++j) {
            bfh[j] = *(const bf16x8*)&Bsh[(wc + j*16 + l16) * 32 + half * 8];
            bfl[j] = *(const bf16x8*)&Bsl[(wc + j*16 + l16) * 32 + half * 8];
        }
        #pragma unroll
        for (int i = 0; i < 4; ++i)
            #pragma unroll
            for (int j = 0; j < 4; ++j) {
                acc[i][j] = __builtin_amdgcn_mfma_f32_16x16x32_bf16(afh[i], bfh[j], acc[i][j], 0, 0, 0);
                acc[i][j] = __builtin_amdgcn_mfma_f32_16x16x32_bf16(afh[i], bfl[j], acc[i][j], 0, 0, 0);
                acc[i][j] = __builtin_amdgcn_mfma_f32_16x16x32_bf16(afl[i], bfh[j], acc[i][j], 0, 0, 0);
            }
    }

    // C/D layout: col = lane&15, row = (lane>>4)*4 + reg   [m89/m91 verified]
    #pragma unroll
    for (int i = 0; i < 4; ++i)
        #pragma unroll
        for (int j = 0; j < 4; ++j)
            #pragma unroll
            for (int r = 0; r < 4; ++r) {
                int row = m0 + wr + i * 16 + half * 4 + r;
                int col = n0 + wc + j * 16 + l16;
                float val = acc[i][j][r];
                if (TRANSC) stc(C + (size_t)col * ldc + row, val);
                else        stc(C + (size_t)row * ldc + col, val);
            }
}

// ---------------------------------------------------------------------------
// Kernel 3: plain bf16 MFMA GEMM C = A*B^T, fused silu, FP32 output.
// A: bf16 [M,K] element pitch lda (packed P view); B: bf16 [N,K] (vT).
// ---------------------------------------------------------------------------
__global__ __launch_bounds__(256, 2) void gemm_bt_silu(
    const u16* __restrict__ A, int lda,
    const u16* __restrict__ B, int ldb,
    float* __restrict__ C, int ldc, int K)
{
    __shared__ __align__(16) u16 As[128 * 32];
    __shared__ __align__(16) u16 Bs[128 * 32];

    const int tid  = threadIdx.x;
    const int lane = tid & 63;
    const int wave = tid >> 6;
    const int m0   = blockIdx.y * 128;
    const int n0   = blockIdx.x * 128;
    const int wr   = (wave >> 1) * 64;
    const int wc   = (wave & 1) * 64;
    const int half = lane >> 4;
    const int l16  = lane & 15;

    f32x4 acc[4][4] = {};
    const int arow = tid >> 2;
    const int acol = (tid & 3) * 8;

    for (int k0 = 0; k0 < K; k0 += 32) {
        bf16x8 a0 = *(const bf16x8*)(A + (size_t)(m0 + arow)      * lda + k0 + acol);
        bf16x8 a1 = *(const bf16x8*)(A + (size_t)(m0 + 64 + arow) * lda + k0 + acol);
        bf16x8 b0 = *(const bf16x8*)(B + (size_t)(n0 + arow)      * ldb + k0 + acol);
        bf16x8 b1 = *(const bf16x8*)(B + (size_t)(n0 + 64 + arow) * ldb + k0 + acol);

        __syncthreads();
        *(bf16x8*)&As[tid * 8]        = a0;
        *(bf16x8*)&As[2048 + tid * 8] = a1;
        *(bf16x8*)&Bs[tid * 8]        = b0;
        *(bf16x8*)&Bs[2048 + tid * 8] = b1;
        __syncthreads();

        bf16x8 af[4], bfr[4];
        #pragma unroll
        for (int i = 0; i < 4; ++i)
            af[i] = *(const bf16x8*)&As[(wr + i*16 + l16) * 32 + half * 8];
        #pragma unroll
        for (int j = 0; j < 4; ++j)
            bfr[j] = *(const bf16x8*)&Bs[(wc + j*16 + l16) * 32 + half * 8];
        #pragma unroll
        for (int i = 0; i < 4; ++i)
            #pragma unroll
            for (int j = 0; j < 4; ++j)
                acc[i][j] = __builtin_amdgcn_mfma_f32_16x16x32_bf16(af[i], bfr[j], acc[i][j], 0, 0, 0);
    }

    #pragma unroll
    for (int i = 0; i < 4; ++i)
        #pragma unroll
        for (int j = 0; j < 4; ++j)
            #pragma unroll
            for (int r = 0; r < 4; ++r) {
                int row = m0 + wr + i * 16 + half * 4 + r;
                int col = n0 + wc + j * 16 + l16;
                float v = acc[i][j][r];
                v = v / (1.0f + __expf(-v));   // silu
                C[(size_t)row * ldc + col] = v;
            }
}

// ---------------------------------------------------------------------------
// Kernel 4: row softmax over fp32 [SEQ, SEQ]; writes bf16 P packed in-place
// into each row's own fp32 footprint (element pitch 2*SEQ u16 per row).
// ---------------------------------------------------------------------------
__global__ __launch_bounds__(256) void softmax_rows(float* __restrict__ S)
{
    const int row  = blockIdx.x;
    const int t    = threadIdx.x;
    const int lane = t & 63, wave = t >> 6;
    float* rp = S + (size_t)row * SEQ;

    float v[16];
    #pragma unroll
    for (int i = 0; i < 4; ++i) {
        float4 f = *(const float4*)(rp + i * 1024 + t * 4);
        v[i*4+0] = f.x; v[i*4+1] = f.y; v[i*4+2] = f.z; v[i*4+3] = f.w;
    }

    float m = v[0];
    #pragma unroll
    for (int i = 1; i < 16; ++i) m = fmaxf(m, v[i]);
    #pragma unroll
    for (int off = 32; off > 0; off >>= 1) m = fmaxf(m, __shfl_down(m, off));
    __shared__ float red[4];
    if (lane == 0) red[wave] = m;
    __syncthreads();
    m = fmaxf(fmaxf(red[0], red[1]), fmaxf(red[2], red[3]));
    __syncthreads();

    float s = 0.0f;
    #pragma unroll
    for (int i = 0; i < 16; ++i) { v[i] = __expf(v[i] - m); s += v[i]; }
    #pragma unroll
    for (int off = 32; off > 0; off >>= 1) s += __shfl_down(s, off);
    if (lane == 0) red[wave] = s;
    __syncthreads();
    s = red[0] + red[1] + red[2] + red[3];
    float inv = 1.0f / s;

    u16* op = (u16*)rp;
    #pragma unroll
    for (int i = 0; i < 4; ++i) {
        ushort4 o;
        o.x = f2bf(v[i*4+0] * inv);
        o.y = f2bf(v[i*4+1] * inv);
        o.z = f2bf(v[i*4+2] * inv);
        o.w = f2bf(v[i*4+3] * inv);
        *(ushort4*)(op + i * 1024 + t * 4) = o;
    }
}

// ---------------------------------------------------------------------------
extern "C" void kernel_launch(void* const* d_in, const int* in_sizes, int n_in,
                              void* d_out, int out_size, void* d_ws, size_t ws_size,
                              hipStream_t stream)
{
    // x int32; emb/norm_w/Wq/Wk/Wv fp32; OUTPUT fp32 (R7-proven contract)
    const int*   x   = (const int*)d_in[0];
    const float* emb = (const float*)d_in[1];
    const float* nw  = (const float*)d_in[2];
    const float* Wq  = (const float*)d_in[3];
    const float* Wk  = (const float*)d_in[4];
    const float* Wv  = (const float*)d_in[5];
    float* out = (float*)d_out;

    // ws layout (104 MB, R7-proven size; h overlaps Sc head, dies before
    // the Sc GEMM writes):
    char* ws = (char*)d_ws;
    float* q  = (float*)(ws);                   // [ 0,16) MB [SEQ,DIM] fp32
    float* k  = (float*)(ws + (16u << 20));     // [16,32) MB [SEQ,DIM] fp32
    u16*   vT = (u16*)  (ws + (32u << 20));     // [32,40) MB [DIM,SEQ] bf16
    float* Sc = (float*)(ws + (40u << 20));     // [40,104) MB [SEQ,SEQ] fp32
    float* h  = (float*)(ws + (40u << 20));     // [40,56) MB [SEQ,DIM] fp32

    embed_rmsnorm<<<SEQ, 256, 0, stream>>>(x, emb, nw, h);

    dim3 gqkv(DIM / 128, SEQ / 128);
    gemm_f32in<float, false><<<gqkv, 256, 0, stream>>>(h, DIM, Wq, DIM, q,  DIM, DIM);
    gemm_f32in<float, false><<<gqkv, 256, 0, stream>>>(h, DIM, Wk, DIM, k,  DIM, DIM);
    gemm_f32in<u16,   true ><<<gqkv, 256, 0, stream>>>(h, DIM, Wv, DIM, vT, SEQ, DIM);

    dim3 gs(SEQ / 128, SEQ / 128);
    gemm_f32in<float, false><<<gs, 256, 0, stream>>>(q, DIM, k, DIM, Sc, SEQ, DIM);

    softmax_rows<<<SEQ, 256, 0, stream>>>(Sc);

    dim3 gpv(DIM / 128, SEQ / 128);
    // P viewed as bf16 with element pitch 8192; vT is B^T layout [DIM, SEQ]
    gemm_bt_silu<<<gpv, 256, 0, stream>>>((const u16*)Sc, 2 * SEQ, vT, SEQ, out, DIM, SEQ);
}